// Round 23
// baseline (25.159 us; speedup 1.0000x reference)
//
#include <hip/hip_runtime.h>
#include <hip/hip_bf16.h>

#define CIN 32
#define HW 64
#define KK 64
#define NLEAF 8
#define PADDING 2
#define TH 4                    // tile rows
#define TCW 16                  // tile cols
#define WR 8                    // window rows = TH + 4
#define WC 20                   // window cols = TCW + 4
#define WPOS (CIN * WR * WC)    // 5120 positions; f32x2 each -> 40960 B LDS

typedef float f32x2 __attribute__((ext_vector_type(2)));

__device__ __constant__ float d_C[16][4] = {
    {0, 0, 0, 0},  {0, 0, 0, 1},  {0, 1, 0, -1}, {0, 1, 0, 0},
    {0, 0, 1, -1}, {0, 0, 1, 0},  {0, 1, 1, -2}, {0, 1, 1, -1},
    {1, -1, -1, 1},{1, -1, -1, 2},{1, 0, -1, 0}, {1, 0, -1, 1},
    {1, -1, 0, 0}, {1, -1, 0, 1}, {1, 0, 0, -1}, {1, 0, 0, 0}
};

// Fully parallel prep: 4 blocks x 256 threads = 1024 threads.
// loffA[k*16+n] = BYTE offset of leaf (c,dh,dw) in the f32x2 window;
// tid<960: one coefA node each.
__global__ __launch_bounds__(256) void prep_kernel(
    const int* __restrict__ idx_h, const int* __restrict__ idx_w, const int* __restrict__ idx_c,
    const float* __restrict__ w0, const float* __restrict__ w1,
    const float* __restrict__ w2, const float* __restrict__ w3,
    float* __restrict__ coefA, int* __restrict__ loffA)
{
    int tid = blockIdx.x * 256 + threadIdx.x;   // 0..1023

    {
        int k = tid >> 4, n = tid & 15;
        int s = n >> 3, leaf = n & 7;
        int o = s * (KK * NLEAF) + k * NLEAF + leaf;
        loffA[tid] = (idx_c[o] * (WR * WC) + idx_h[o] * WC + idx_w[o]) * 8;
    }

    if (tid < KK * 15) {
        int k = tid / 15, node = tid % 15;
        const float* wp; int n;
        if (node < 8)       { wp = w0; n = node; }
        else if (node < 12) { wp = w1; n = node - 8; }
        else if (node < 14) { wp = w2; n = node - 12; }
        else                { wp = w3; n = 0; }
        const float4* lp = (const float4*)(wp + (size_t)(n * KK + k) * 16);
        float4 L0 = lp[0], L1 = lp[1], L2 = lp[2], L3 = lp[3];
        float l[16] = {L0.x, L0.y, L0.z, L0.w, L1.x, L1.y, L1.z, L1.w,
                       L2.x, L2.y, L2.z, L2.w, L3.x, L3.y, L3.z, L3.w};
        float m = l[0];
        #pragma unroll
        for (int g = 1; g < 16; ++g) m = fmaxf(m, l[g]);
        float p[16], s = 0.f;
        #pragma unroll
        for (int g = 0; g < 16; ++g) { p[g] = __expf(l[g] - m); s += p[g]; }
        float inv = 1.f / s;
        float c0 = 0, c1 = 0, c2 = 0, c3 = 0;
        #pragma unroll
        for (int g = 0; g < 16; ++g) {
            float w = p[g] * inv;
            c0 = fmaf(w, d_C[g][0], c0);
            c1 = fmaf(w, d_C[g][1], c1);
            c2 = fmaf(w, d_C[g][2], c2);
            c3 = fmaf(w, d_C[g][3], c3);
        }
        float* o = coefA + (k * 60 + node * 4);
        o[0] = c0; o[1] = c1; o[2] = c2; o[3] = c3;
    }
}

__device__ __forceinline__ f32x2 bc(float s) { return (f32x2){s, s}; }
__device__ __forceinline__ f32x2 gate2(const float* c, f32x2 a, f32x2 b) {
    return __builtin_elementwise_fma(b,
               __builtin_elementwise_fma(a, bc(c[3]), bc(c[2])),
               __builtin_elementwise_fma(a, bc(c[1]), bc(c[0])));
}

// blockIdx = tile*8 + bp (XCD-pinned: a batch-pair's 64 blocks share one
// XCD's L2). 512 threads = 8 waves; wave w covers k in [8w, 8w+8) -> ONE
// staged window serves ALL 64 k. Window = 40960 B -> 4 blocks/CU = 32
// waves/CU (stage/compute stagger across 4 block-rounds). 8 waves/SIMD
// permits 256 VGPR/wave, so the hoisted ga[8][16] address file fits.
// lane = pixel of the 4x16 tile; f32x2 = 2 batch images (ds_read_b64,
// 2-lane/bank aliasing = free).
__global__ __launch_bounds__(512) void logic_conv_kernel(
    const float* __restrict__ x, const int* __restrict__ loffA,
    const float* __restrict__ coefA, float* __restrict__ out)
{
    __shared__ f32x2 xt[WPOS];

    int tid = threadIdx.x;
    int bp  = blockIdx.x & 7;          // batch-pair == XCD slot
    int t   = blockIdx.x >> 3;         // tile 0..63
    int r0  = (t >> 2) * TH;
    int c0  = (t & 3) * TCW;

    int lane = tid & 63, wave = tid >> 6;
    int kbase = __builtin_amdgcn_readfirstlane(wave << 3);
    int tr = lane >> 4, tc = lane & 15;
    int pxb = (tr * WC + tc) * 8;      // per-lane byte offset in window

    // ---- hoisted gather addresses: 8 k x 16 leaves (compile-time indexed;
    //      the loffA s_loads overlap the staging global loads) ----
    int ga[8][16];
    #pragma unroll
    for (int j = 0; j < 8; ++j) {
        const int* L = loffA + ((kbase + j) << 4);
        #pragma unroll
        for (int n = 0; n < 16; ++n)
            ga[j][n] = L[n] + pxb;
    }

    const float* xb0 = x + (size_t)(2 * bp) * (CIN * HW * HW);
    const float* xb1 = xb0 + (CIN * HW * HW);

    // Stage interleaved padded 32x8x20 windows (10 positions/thread).
    #pragma unroll
    for (int i = 0; i < 10; ++i) {
        int e  = tid + i * 512;
        int c  = e / (WR * WC);
        int r  = e - c * (WR * WC);
        int rr = r / WC;
        int cc = r - rr * WC;
        int ih = r0 + rr - PADDING, iw = c0 + cc - PADDING;
        f32x2 v = {0.f, 0.f};
        if ((unsigned)ih < HW && (unsigned)iw < HW) {
            int go = (c * HW + ih) * HW + iw;
            v.x = xb0[go];
            v.y = xb1[go];
        }
        xt[e] = v;
    }
    __syncthreads();

    int pxout = (r0 + tr) * HW + (c0 + tc);
    float* outB0 = out + ((size_t)(2 * bp) << 18);
    float* outB1 = outB0 + (1 << 18);
    const char* xtb = (const char*)xt;

    #pragma unroll
    for (int j = 0; j < 8; ++j) {
        const float* C = coefA + (kbase + j) * 60;

        f32x2 g[16];
        #pragma unroll
        for (int n = 0; n < 16; ++n)
            g[n] = *(const f32x2*)(xtb + ga[j][n]);

        f32x2 v[8];
        #pragma unroll
        for (int n = 0; n < 8; ++n)
            v[n] = gate2(C + 4 * n, g[n], g[8 + n]);
        f32x2 u[4];
        #pragma unroll
        for (int n = 0; n < 4; ++n)
            u[n] = gate2(C + 32 + 4 * n, v[2 * n], v[2 * n + 1]);
        f32x2 t0 = gate2(C + 48, u[0], u[1]);
        f32x2 t1 = gate2(C + 52, u[2], u[3]);
        f32x2 r  = gate2(C + 56, t0, t1);

        int ko = ((kbase + j) << 12) + pxout;
        __builtin_nontemporal_store(r.x, &outB0[ko]);
        __builtin_nontemporal_store(r.y, &outB1[ko]);
    }
}

extern "C" void kernel_launch(void* const* d_in, const int* in_sizes, int n_in,
                              void* d_out, int out_size, void* d_ws, size_t ws_size,
                              hipStream_t stream) {
    const float* x     = (const float*)d_in[0];
    const int*   idx_h = (const int*)d_in[1];
    const int*   idx_w = (const int*)d_in[2];
    const int*   idx_c = (const int*)d_in[3];
    const float* w0    = (const float*)d_in[4];
    const float* w1    = (const float*)d_in[5];
    const float* w2    = (const float*)d_in[6];
    const float* w3    = (const float*)d_in[7];
    float* out   = (float*)d_out;

    float* coefA = (float*)d_ws;                      // 15,360 B
    int*   loffA = (int*)((char*)d_ws + 16384);       // 4,096 B

    hipLaunchKernelGGL(prep_kernel, dim3(4), dim3(256), 0, stream,
                       idx_h, idx_w, idx_c, w0, w1, w2, w3, coefA, loffA);
    // 64 tiles * 8 batch-pairs = 512 blocks, 512 threads, 40960 B LDS
    hipLaunchKernelGGL(logic_conv_kernel, dim3(512), dim3(512), 0, stream,
                       x, loffA, coefA, out);
}